// Round 14
// baseline (110.206 us; speedup 1.0000x reference)
//
#include <hip/hip_runtime.h>
#include <hip/hip_bf16.h>
#include <math.h>

// Shapes: B=2, Le=250, Ld=150, N=400, Wl=16, Vin=128, E=64, F=128, K=5
//         H=8, hid=32, d=256, Vout=5000
// Inputs fp32, output fp32 (verified round 4). fixed_graph/dg_* dead:
// adj=clip(sigmoid+fixed,0,1) strictly positive => unmasked softmax.
// Round-13 -> 14: wh sections used Wp[d*32] scalar loads (256-deep serial
// chain, 256B/wave/instr). Now attW is transposed once in prep to
// attWT[h][k][d]; each thread streams its own contiguous 1KB row with 64
// float4 loads (16B/lane sweet spot, 4x fewer load instrs), x operand is an
// LDS float4 broadcast. Pipeline unchanged:
//   S1 prep: conv table T + out_W->bf16 + attW transpose
//   S2 conv+hst+Wh1 fused (x in LDS only)
//   S3 attn1 (50,16) -> x1
//   S4 wh2 (400) -> Wh2/f1B/f2B
//   S5 attn2 (19,16) decoder rows only (clamped dup writes benign)
//   S6 out

__device__ __forceinline__ float bf2f_raw(unsigned int u) {
    union { unsigned int i; float f; } cv; cv.i = u << 16; return cv.f;
}
__device__ __forceinline__ unsigned short f2bf(float f) {
    __hip_bfloat16 h = __float2bfloat16(f);
    return *reinterpret_cast<unsigned short*>(&h);
}

// ---------- S1: table T (blocks 0..127) + out_W->bf16 (128..2627)
//              + attW -> attWT[h][k][d] (2628..2635)
__global__ __launch_bounds__(256) void k_prep(const float* emb, const float* convw,
                                              float* T, const float* W,
                                              unsigned short* Wb,
                                              const float* attW, float* attWT) {
    int bid = blockIdx.x, t = threadIdx.x;
    if (bid < 128) {
        int v = bid;
        __shared__ float er[64];
        if (t < 64) er[t] = emb[v * 64 + t];
        __syncthreads();
        if (t < 128) {
            float acc[5] = {0.f, 0.f, 0.f, 0.f, 0.f};
            const float* w = convw + t * 320;          // convw[f][e][k5]
            for (int e = 0; e < 64; ++e) {
                float xe = er[e];
#pragma unroll
                for (int k = 0; k < 5; ++k) acc[k] += xe * w[e * 5 + k];
            }
#pragma unroll
            for (int k = 0; k < 5; ++k) T[(k * 128 + v) * 128 + t] = acc[k];
        }
    } else if (bid < 2628) {
        int i0 = (bid - 128) * 512 + t * 2;            // 2500 blocks * 512
        if (i0 < 256 * 5000) {
            float2 w2 = *reinterpret_cast<const float2*>(W + i0);
            unsigned int u = ((unsigned int)f2bf(w2.y) << 16) | f2bf(w2.x);
            *reinterpret_cast<unsigned int*>(Wb + i0) = u;
        }
    } else {
        int h = bid - 2628;                            // 8 blocks, one head each
        const float* src = attW + h * 8192;            // [d][k], 32KB = L1-resident
        float* dst = attWT + h * 8192;                 // [k][d]
        for (int k = 0; k < 32; ++k)
            dst[k * 256 + t] = src[t * 32 + k];
    }
}

// ---------- S2: char conv + bias + relu + maxpool + hst + Wh1 + f1/f2.
__global__ __launch_bounds__(256) void k_convwh(const int* enc, const int* dec,
                                                const float* convb, const float* T,
                                                const float* hstW, const float* hstb,
                                                const float* attWT,
                                                const float* a1g, const float* a2g,
                                                float* Wh, float* f1, float* f2) {
    int w0 = blockIdx.x * 2, t = threadIdx.x;          // grid 400
    __shared__ int ids[2][16];
    __shared__ float xcl[2][128];
    __shared__ float x0[2][256];
    if (t < 32) {
        int r = t >> 4, c = t & 15;
        int w = w0 + r, b = w / 400, n = w % 400;
        ids[r][c] = (n < 250) ? enc[(b * 250 + n) * 16 + c]
                              : dec[(b * 150 + (n - 250)) * 16 + c];
    }
    __syncthreads();
    {
        int r = t >> 7, f = t & 127;                   // conv: all 256 active
        float best = -1e30f;
        for (int p = 0; p < 16; ++p) {
            float s = 0.f;
#pragma unroll
            for (int k = 0; k < 5; ++k) {
                int q = p + k - 2;
                if (q >= 0 && q < 16) s += T[(k * 128 + ids[r][q]) * 128 + f];
            }
            best = fmaxf(best, s);
        }
        xcl[r][f] = fmaxf(best + convb[f], 0.f);
    }
    __syncthreads();
    {
        float acc0 = hstb[t], acc1 = acc0;             // hst: 2 rows share loads
        for (int c = 0; c < 128; ++c) {
            float wv = hstW[c * 256 + t];
            acc0 += xcl[0][c] * wv;
            acc1 += xcl[1][c] * wv;
        }
        x0[0][t] = acc0;
        x0[1][t] = acc1;
    }
    __syncthreads();
    // Wh1: thread (h,k) streams its contiguous attWT row, x0 LDS broadcast
    float acc0 = 0.f, acc1 = 0.f;
    const float4* Wp4 = (const float4*)(attWT + t * 256);   // t = h*32+k
#pragma unroll 8
    for (int dq = 0; dq < 64; ++dq) {
        float4 w4 = Wp4[dq];
        float4 xa = *(const float4*)&x0[0][dq * 4];
        float4 xb = *(const float4*)&x0[1][dq * 4];
        acc0 += xa.x * w4.x + xa.y * w4.y + xa.z * w4.z + xa.w * w4.w;
        acc1 += xb.x * w4.x + xb.y * w4.y + xb.z * w4.z + xb.w * w4.w;
    }
    int h = t >> 5, k = t & 31;
    float a1v = a1g[t], a2v = a2g[t];
    int b = w0 / 400;
    int bh = b * 8 + h;
    float accs[2] = {acc0, acc1};
#pragma unroll
    for (int rw = 0; rw < 2; ++rw) {
        int n = (w0 + rw) % 400;
        Wh[(bh * 400 + n) * 32 + k] = accs[rw];
        float v1 = accs[rw] * a1v, v2 = accs[rw] * a2v;
#pragma unroll
        for (int mm = 16; mm >= 1; mm >>= 1) {
            v1 += __shfl_xor(v1, mm, 64);
            v2 += __shfl_xor(v2, mm, 64);
        }
        if (k == 0) { f1[bh * 400 + n] = v1; f2[bh * 400 + n] = v2; }
    }
}

// ---------- S4: Wh2 + fused f1/f2 from global x. 2 rows/block.
__global__ __launch_bounds__(256) void k_wh(const float* x, const float* attWT,
                                            const float* a1g, const float* a2g,
                                            float* Wh, float* f1, float* f2) {
    int blk = blockIdx.x, t = threadIdx.x;             // grid 400
    int w0 = blk * 2;
    __shared__ float xr[2][256];
    for (int i = t; i < 512; i += 256) xr[i >> 8][i & 255] = x[w0 * 256 + i];
    __syncthreads();
    float acc0 = 0.f, acc1 = 0.f;
    const float4* Wp4 = (const float4*)(attWT + t * 256);
#pragma unroll 8
    for (int dq = 0; dq < 64; ++dq) {
        float4 w4 = Wp4[dq];
        float4 xa = *(const float4*)&xr[0][dq * 4];
        float4 xb = *(const float4*)&xr[1][dq * 4];
        acc0 += xa.x * w4.x + xa.y * w4.y + xa.z * w4.z + xa.w * w4.w;
        acc1 += xb.x * w4.x + xb.y * w4.y + xb.z * w4.z + xb.w * w4.w;
    }
    int h = t >> 5, k = t & 31;
    float a1v = a1g[t], a2v = a2g[t];
    int b = w0 / 400;
    int bh = b * 8 + h;
    float accs[2] = {acc0, acc1};
#pragma unroll
    for (int rw = 0; rw < 2; ++rw) {
        int n = (w0 + rw) % 400;
        Wh[(bh * 400 + n) * 32 + k] = accs[rw];
        float v1 = accs[rw] * a1v, v2 = accs[rw] * a2v;
#pragma unroll
        for (int mm = 16; mm >= 1; mm >>= 1) {
            v1 += __shfl_xor(v1, mm, 64);
            v2 += __shfl_xor(v2, mm, 64);
        }
        if (k == 0) { f1[bh * 400 + n] = v1; f2[bh * 400 + n] = v2; }
    }
}

// ---------- S3/S5: softmax + PV + elu. One bh x 8 rows per block.
__global__ __launch_bounds__(256) void k_attn(const float* Wh, const float* f1g,
                                              const float* f2g, float* xout,
                                              int n_base) {
    int tile = blockIdx.x, bh = blockIdx.y;
    int b = bh >> 3, h = bh & 7;
    int t = threadIdx.x;
    int n0 = n_base + tile * 8;
    __shared__ float f2l[400];
    __shared__ float4 plT[400];                    // p transposed: [m][4 rows]
    __shared__ float f1l[8];
    __shared__ float red[4][8][4][4];              // [wave][kq][rw][c]
    __shared__ float sred[2][4][4];
    __shared__ float wmax[4];

    float fm = -1e30f;
    for (int m = t; m < 400; m += 256) {
        float v = f2g[bh * 400 + m];
        f2l[m] = v;
        fm = fmaxf(fm, v);
    }
    if (t < 8) {
        int n = n0 + t; if (n > 399) n = 399;
        f1l[t] = f1g[bh * 400 + n];
    }
#pragma unroll
    for (int mm = 32; mm >= 1; mm >>= 1) fm = fmaxf(fm, __shfl_xor(fm, mm, 64));
    if ((t & 63) == 0) wmax[t >> 6] = fm;
    __syncthreads();
    float fmax2 = fmaxf(fmaxf(wmax[0], wmax[1]), fmaxf(wmax[2], wmax[3]));

    int g = t & 7, kq = (t >> 3) & 7, wv = t >> 6;
    int gm = g + 8 * wv;                           // m-group 0..31
    const float4* WhG = (const float4*)(Wh + bh * 12800);
    for (int it = 0; it < 2; ++it) {
        float f1a = f1l[it * 4 + 0], f1b = f1l[it * 4 + 1];
        float f1c = f1l[it * 4 + 2], f1d = f1l[it * 4 + 3];
        float rm0 = f1a + fmax2; rm0 = rm0 > 0.f ? rm0 : 0.2f * rm0;
        float rm1 = f1b + fmax2; rm1 = rm1 > 0.f ? rm1 : 0.2f * rm1;
        float rm2 = f1c + fmax2; rm2 = rm2 > 0.f ? rm2 : 0.2f * rm2;
        float rm3 = f1d + fmax2; rm3 = rm3 > 0.f ? rm3 : 0.2f * rm3;
        float ps0 = 0.f, ps1 = 0.f, ps2 = 0.f, ps3 = 0.f;
        for (int m = t; m < 400; m += 256) {
            float f2v = f2l[m];
            float e0 = f1a + f2v; e0 = e0 > 0.f ? e0 : 0.2f * e0;
            float e1 = f1b + f2v; e1 = e1 > 0.f ? e1 : 0.2f * e1;
            float e2 = f1c + f2v; e2 = e2 > 0.f ? e2 : 0.2f * e2;
            float e3 = f1d + f2v; e3 = e3 > 0.f ? e3 : 0.2f * e3;
            float4 pv;
            pv.x = __expf(e0 - rm0); ps0 += pv.x;
            pv.y = __expf(e1 - rm1); ps1 += pv.y;
            pv.z = __expf(e2 - rm2); ps2 += pv.z;
            pv.w = __expf(e3 - rm3); ps3 += pv.w;
            plT[m] = pv;
        }
#pragma unroll
        for (int mm = 32; mm >= 1; mm >>= 1) {
            ps0 += __shfl_xor(ps0, mm, 64);
            ps1 += __shfl_xor(ps1, mm, 64);
            ps2 += __shfl_xor(ps2, mm, 64);
            ps3 += __shfl_xor(ps3, mm, 64);
        }
        if ((t & 63) == 0) {
            int wq = t >> 6;
            sred[it & 1][0][wq] = ps0; sred[it & 1][1][wq] = ps1;
            sred[it & 1][2][wq] = ps2; sred[it & 1][3][wq] = ps3;
        }
        __syncthreads();
        float a[4][4];
#pragma unroll
        for (int rr = 0; rr < 4; ++rr)
#pragma unroll
            for (int c = 0; c < 4; ++c) a[rr][c] = 0.f;
#pragma unroll 4
        for (int m = gm; m < 400; m += 32) {
            float4 w4 = WhG[m * 8 + kq];
            float4 p4 = plT[m];
            a[0][0] += p4.x * w4.x; a[0][1] += p4.x * w4.y; a[0][2] += p4.x * w4.z; a[0][3] += p4.x * w4.w;
            a[1][0] += p4.y * w4.x; a[1][1] += p4.y * w4.y; a[1][2] += p4.y * w4.z; a[1][3] += p4.y * w4.w;
            a[2][0] += p4.z * w4.x; a[2][1] += p4.z * w4.y; a[2][2] += p4.z * w4.z; a[2][3] += p4.z * w4.w;
            a[3][0] += p4.w * w4.x; a[3][1] += p4.w * w4.y; a[3][2] += p4.w * w4.z; a[3][3] += p4.w * w4.w;
        }
#pragma unroll
        for (int rr = 0; rr < 4; ++rr)
#pragma unroll
            for (int c = 0; c < 4; ++c) {
                float v = a[rr][c];
                v += __shfl_xor(v, 1, 64);             // DPP, off the LDS pipe
                v += __shfl_xor(v, 2, 64);
                v += __shfl_xor(v, 4, 64);
                a[rr][c] = v;
            }
        if (g == 0) {
#pragma unroll
            for (int rr = 0; rr < 4; ++rr)
#pragma unroll
                for (int c = 0; c < 4; ++c) red[wv][kq][rr][c] = a[rr][c];
        }
        __syncthreads();
        if (t < 128) {
            int rw3 = t >> 5, kk = t & 31;
            int q3 = kk >> 2, c3 = kk & 3;
            float s = sred[it & 1][rw3][0] + sred[it & 1][rw3][1]
                    + sred[it & 1][rw3][2] + sred[it & 1][rw3][3];
            float o = (red[0][q3][rw3][c3] + red[1][q3][rw3][c3]
                     + red[2][q3][rw3][c3] + red[3][q3][rw3][c3]) / s;
            o = o > 0.f ? o : (__expf(o) - 1.f);       // elu
            int n = n0 + it * 4 + rw3;
            if (n > 399) n = 399;                      // clamped dup: same value
            xout[(b * 400 + n) * 256 + h * 32 + kk] = o;
        }
        __syncthreads();
    }
}

// ---------- S6: out[r][v] = sum_d x[b,250+dn,d]*Wb[d][v] + b[v]
__global__ __launch_bounds__(256) void k_out(const float* x, const unsigned short* Wb,
                                             const float* bias, float* out) {
    int vt = blockIdx.x, rg = blockIdx.y, t = threadIdx.x;  // grid (10,50)
    __shared__ float xr[6][256];
    int r0 = rg * 6;
    int b = r0 / 150, n0 = 250 + (r0 % 150);
    for (int i = t; i < 1536; i += 256) {
        int rr = i >> 8, dd = i & 255;
        xr[rr][dd] = x[(b * 400 + n0 + rr) * 256 + dd];
    }
    __syncthreads();
    int v = vt * 512 + t * 2;
    if (v >= 5000) return;
    float acc[6][2];
#pragma unroll
    for (int rr = 0; rr < 6; ++rr) { acc[rr][0] = 0.f; acc[rr][1] = 0.f; }
    const unsigned short* Wp = Wb + v;
#pragma unroll 8
    for (int dd = 0; dd < 256; ++dd) {
        unsigned int wu = *reinterpret_cast<const unsigned int*>(Wp + dd * 5000);
        float w0 = bf2f_raw(wu & 0xFFFFu);
        float w1 = bf2f_raw(wu >> 16);
#pragma unroll
        for (int rr = 0; rr < 6; ++rr) {
            float xv = xr[rr][dd];
            acc[rr][0] += xv * w0;
            acc[rr][1] += xv * w1;
        }
    }
    float b0 = bias[v], b1 = bias[v + 1];
#pragma unroll
    for (int rr = 0; rr < 6; ++rr) {
        out[(r0 + rr) * 5000 + v]     = acc[rr][0] + b0;
        out[(r0 + rr) * 5000 + v + 1] = acc[rr][1] + b1;
    }
}

extern "C" void kernel_launch(void* const* d_in, const int* in_sizes, int n_in,
                              void* d_out, int out_size, void* d_ws, size_t ws_size,
                              hipStream_t stream) {
    const int*   enc   = (const int*)d_in[0];
    const int*   dec   = (const int*)d_in[1];
    const float* emb   = (const float*)d_in[3];
    const float* convw = (const float*)d_in[4];
    const float* convb = (const float*)d_in[5];
    const float* hstW  = (const float*)d_in[6];
    const float* hstb  = (const float*)d_in[7];
    const float* attW  = (const float*)d_in[15];
    const float* a1    = (const float*)d_in[16];
    const float* a2    = (const float*)d_in[17];
    const float* outW  = (const float*)d_in[18];
    const float* outb  = (const float*)d_in[19];
    float* out = (float*)d_out;

    char* ws = (char*)d_ws;
    float* T    = (float*)ws; ws += 5 * 128 * 128 * 4;
    float* aT   = (float*)ws; ws += 8 * 256 * 32 * 4;     // attWT[h][k][d]
    float* WhA  = (float*)ws; ws += 16 * 400 * 32 * 4;
    float* WhB  = (float*)ws; ws += 16 * 400 * 32 * 4;
    float* f1A  = (float*)ws; ws += 16 * 400 * 4;
    float* f2A  = (float*)ws; ws += 16 * 400 * 4;
    float* f1B  = (float*)ws; ws += 16 * 400 * 4;
    float* f2B  = (float*)ws; ws += 16 * 400 * 4;
    float* x1   = (float*)ws; ws += 800 * 256 * 4;
    float* x2   = (float*)ws; ws += 800 * 256 * 4;
    unsigned short* Wb = (unsigned short*)ws; ws += 256 * 5000 * 2;

    k_prep<<<2636, 256, 0, stream>>>(emb, convw, T, outW, Wb, attW, aT);
    k_convwh<<<400, 256, 0, stream>>>(enc, dec, convb, T, hstW, hstb, aT,
                                      a1, a2, WhA, f1A, f2A);
    k_attn<<<dim3(50, 16), 256, 0, stream>>>(WhA, f1A, f2A, x1, 0);
    k_wh<<<400, 256, 0, stream>>>(x1, aT, a1, a2, WhB, f1B, f2B);
    k_attn<<<dim3(19, 16), 256, 0, stream>>>(WhB, f1B, f2B, x2, 250);
    k_out<<<dim3(10, 50), 256, 0, stream>>>(x2, Wb, outb, out);
}

// Round 15
// 95.295 us; speedup vs baseline: 1.1565x; 1.1565x over previous
//
#include <hip/hip_runtime.h>
#include <hip/hip_bf16.h>
#include <math.h>

// Shapes: B=2, Le=250, Ld=150, N=400, Wl=16, Vin=128, E=64, F=128, K=5
//         H=8, hid=32, d=256, Vout=5000
// Inputs fp32, output fp32 (verified round 4). fixed_graph/dg_* dead:
// adj=clip(sigmoid+fixed,0,1) strictly positive => unmasked softmax.
// ROUND-13 VERBATIM (measured 95.5us, session best). Round-14's attWT
// transpose regressed to 110us: per-thread-contiguous rows made each wave
// load instruction touch 64 cache lines 1KB apart (coalescing is about the
// wave's lanes, not a thread's stream). The Wp[d*32] pattern below is 2x128B
// segments per wave instruction = coalesced.
//   S1 prep: conv table T + out_W->bf16
//   S2 conv+hst+Wh1 fused (x in LDS only)
//   S3 attn1 (50,16) -> x1
//   S4 wh2 (400) -> Wh2/f1B/f2B
//   S5 attn2 (19,16) decoder rows only (clamped dup writes benign)
//   S6 out

__device__ __forceinline__ float bf2f_raw(unsigned int u) {
    union { unsigned int i; float f; } cv; cv.i = u << 16; return cv.f;
}
__device__ __forceinline__ unsigned short f2bf(float f) {
    __hip_bfloat16 h = __float2bfloat16(f);
    return *reinterpret_cast<unsigned short*>(&h);
}

// ---------- S1: conv table T (blocks 0..127) + out_W->bf16 (rest)
__global__ __launch_bounds__(256) void k_prep(const float* emb, const float* convw,
                                              float* T, const float* W,
                                              unsigned short* Wb) {
    int bid = blockIdx.x, t = threadIdx.x;
    if (bid < 128) {
        int v = bid;
        __shared__ float er[64];
        if (t < 64) er[t] = emb[v * 64 + t];
        __syncthreads();
        if (t < 128) {
            float acc[5] = {0.f, 0.f, 0.f, 0.f, 0.f};
            const float* w = convw + t * 320;          // convw[f][e][k5]
            for (int e = 0; e < 64; ++e) {
                float xe = er[e];
#pragma unroll
                for (int k = 0; k < 5; ++k) acc[k] += xe * w[e * 5 + k];
            }
#pragma unroll
            for (int k = 0; k < 5; ++k) T[(k * 128 + v) * 128 + t] = acc[k];
        }
    } else {
        int i0 = (bid - 128) * 512 + t * 2;            // 2500 blocks * 512
        if (i0 < 256 * 5000) {
            float2 w2 = *reinterpret_cast<const float2*>(W + i0);
            unsigned int u = ((unsigned int)f2bf(w2.y) << 16) | f2bf(w2.x);
            *reinterpret_cast<unsigned int*>(Wb + i0) = u;
        }
    }
}

// ---------- S2: char conv + bias + relu + maxpool + hst + Wh1 + f1/f2.
__global__ __launch_bounds__(256) void k_convwh(const int* enc, const int* dec,
                                                const float* convb, const float* T,
                                                const float* hstW, const float* hstb,
                                                const float* attW,
                                                const float* a1g, const float* a2g,
                                                float* Wh, float* f1, float* f2) {
    int w0 = blockIdx.x * 2, t = threadIdx.x;          // grid 400
    __shared__ int ids[2][16];
    __shared__ float xcl[2][128];
    __shared__ float x0[2][256];
    if (t < 32) {
        int r = t >> 4, c = t & 15;
        int w = w0 + r, b = w / 400, n = w % 400;
        ids[r][c] = (n < 250) ? enc[(b * 250 + n) * 16 + c]
                              : dec[(b * 150 + (n - 250)) * 16 + c];
    }
    __syncthreads();
    {
        int r = t >> 7, f = t & 127;                   // conv: all 256 active
        float best = -1e30f;
        for (int p = 0; p < 16; ++p) {
            float s = 0.f;
#pragma unroll
            for (int k = 0; k < 5; ++k) {
                int q = p + k - 2;
                if (q >= 0 && q < 16) s += T[(k * 128 + ids[r][q]) * 128 + f];
            }
            best = fmaxf(best, s);
        }
        xcl[r][f] = fmaxf(best + convb[f], 0.f);
    }
    __syncthreads();
    {
        float acc0 = hstb[t], acc1 = acc0;             // hst: 2 rows share loads
        for (int c = 0; c < 128; ++c) {
            float wv = hstW[c * 256 + t];
            acc0 += xcl[0][c] * wv;
            acc1 += xcl[1][c] * wv;
        }
        x0[0][t] = acc0;
        x0[1][t] = acc1;
    }
    __syncthreads();
    int h = t >> 5, k = t & 31;                        // Wh1: thread (h,k)
    float acc0 = 0.f, acc1 = 0.f;
    const float* Wp = attW + h * 8192 + k;
#pragma unroll 8
    for (int d = 0; d < 256; ++d) {
        float wv = Wp[d * 32];
        acc0 += x0[0][d] * wv;
        acc1 += x0[1][d] * wv;
    }
    float a1v = a1g[t], a2v = a2g[t];
    int b = w0 / 400;
    int bh = b * 8 + h;
    float accs[2] = {acc0, acc1};
#pragma unroll
    for (int rw = 0; rw < 2; ++rw) {
        int n = (w0 + rw) % 400;
        Wh[(bh * 400 + n) * 32 + k] = accs[rw];
        float v1 = accs[rw] * a1v, v2 = accs[rw] * a2v;
#pragma unroll
        for (int mm = 16; mm >= 1; mm >>= 1) {
            v1 += __shfl_xor(v1, mm, 64);
            v2 += __shfl_xor(v2, mm, 64);
        }
        if (k == 0) { f1[bh * 400 + n] = v1; f2[bh * 400 + n] = v2; }
    }
}

// ---------- S4: Wh2 + fused f1/f2 from global x. 2 rows/block.
__global__ __launch_bounds__(256) void k_wh(const float* x, const float* attW,
                                            const float* a1g, const float* a2g,
                                            float* Wh, float* f1, float* f2) {
    int blk = blockIdx.x, t = threadIdx.x;             // grid 400
    int w0 = blk * 2;
    int h = t >> 5, k = t & 31;
    __shared__ float xr[2][256];
    for (int i = t; i < 512; i += 256) xr[i >> 8][i & 255] = x[w0 * 256 + i];
    __syncthreads();
    float acc0 = 0.f, acc1 = 0.f;
    const float* Wp = attW + h * 8192 + k;
#pragma unroll 8
    for (int d = 0; d < 256; ++d) {
        float wv = Wp[d * 32];
        acc0 += xr[0][d] * wv;
        acc1 += xr[1][d] * wv;
    }
    float a1v = a1g[t], a2v = a2g[t];
    int b = w0 / 400;
    int bh = b * 8 + h;
    float accs[2] = {acc0, acc1};
#pragma unroll
    for (int rw = 0; rw < 2; ++rw) {
        int n = (w0 + rw) % 400;
        Wh[(bh * 400 + n) * 32 + k] = accs[rw];
        float v1 = accs[rw] * a1v, v2 = accs[rw] * a2v;
#pragma unroll
        for (int mm = 16; mm >= 1; mm >>= 1) {
            v1 += __shfl_xor(v1, mm, 64);
            v2 += __shfl_xor(v2, mm, 64);
        }
        if (k == 0) { f1[bh * 400 + n] = v1; f2[bh * 400 + n] = v2; }
    }
}

// ---------- S3/S5: softmax + PV + elu. One bh x 8 rows per block (round-9
// form). n_base parameterizes full pass (0) vs decoder-only (250, clamped).
__global__ __launch_bounds__(256) void k_attn(const float* Wh, const float* f1g,
                                              const float* f2g, float* xout,
                                              int n_base) {
    int tile = blockIdx.x, bh = blockIdx.y;
    int b = bh >> 3, h = bh & 7;
    int t = threadIdx.x;
    int n0 = n_base + tile * 8;
    __shared__ float f2l[400];
    __shared__ float4 plT[400];                    // p transposed: [m][4 rows]
    __shared__ float f1l[8];
    __shared__ float red[4][8][4][4];              // [wave][kq][rw][c]
    __shared__ float sred[2][4][4];
    __shared__ float wmax[4];

    float fm = -1e30f;
    for (int m = t; m < 400; m += 256) {
        float v = f2g[bh * 400 + m];
        f2l[m] = v;
        fm = fmaxf(fm, v);
    }
    if (t < 8) {
        int n = n0 + t; if (n > 399) n = 399;
        f1l[t] = f1g[bh * 400 + n];
    }
#pragma unroll
    for (int mm = 32; mm >= 1; mm >>= 1) fm = fmaxf(fm, __shfl_xor(fm, mm, 64));
    if ((t & 63) == 0) wmax[t >> 6] = fm;
    __syncthreads();
    float fmax2 = fmaxf(fmaxf(wmax[0], wmax[1]), fmaxf(wmax[2], wmax[3]));

    int g = t & 7, kq = (t >> 3) & 7, wv = t >> 6;
    int gm = g + 8 * wv;                           // m-group 0..31
    const float4* WhG = (const float4*)(Wh + bh * 12800);
    for (int it = 0; it < 2; ++it) {
        // P1: all 4 rows' p at this thread's m -> plT[m]; denominator partials
        float f1a = f1l[it * 4 + 0], f1b = f1l[it * 4 + 1];
        float f1c = f1l[it * 4 + 2], f1d = f1l[it * 4 + 3];
        float rm0 = f1a + fmax2; rm0 = rm0 > 0.f ? rm0 : 0.2f * rm0;
        float rm1 = f1b + fmax2; rm1 = rm1 > 0.f ? rm1 : 0.2f * rm1;
        float rm2 = f1c + fmax2; rm2 = rm2 > 0.f ? rm2 : 0.2f * rm2;
        float rm3 = f1d + fmax2; rm3 = rm3 > 0.f ? rm3 : 0.2f * rm3;
        float ps0 = 0.f, ps1 = 0.f, ps2 = 0.f, ps3 = 0.f;
        for (int m = t; m < 400; m += 256) {
            float f2v = f2l[m];
            float e0 = f1a + f2v; e0 = e0 > 0.f ? e0 : 0.2f * e0;
            float e1 = f1b + f2v; e1 = e1 > 0.f ? e1 : 0.2f * e1;
            float e2 = f1c + f2v; e2 = e2 > 0.f ? e2 : 0.2f * e2;
            float e3 = f1d + f2v; e3 = e3 > 0.f ? e3 : 0.2f * e3;
            float4 pv;
            pv.x = __expf(e0 - rm0); ps0 += pv.x;
            pv.y = __expf(e1 - rm1); ps1 += pv.y;
            pv.z = __expf(e2 - rm2); ps2 += pv.z;
            pv.w = __expf(e3 - rm3); ps3 += pv.w;
            plT[m] = pv;
        }
#pragma unroll
        for (int mm = 32; mm >= 1; mm >>= 1) {
            ps0 += __shfl_xor(ps0, mm, 64);
            ps1 += __shfl_xor(ps1, mm, 64);
            ps2 += __shfl_xor(ps2, mm, 64);
            ps3 += __shfl_xor(ps3, mm, 64);
        }
        if ((t & 63) == 0) {
            int wq = t >> 6;
            sred[it & 1][0][wq] = ps0; sred[it & 1][1][wq] = ps1;
            sred[it & 1][2][wq] = ps2; sred[it & 1][3][wq] = ps3;
        }
        __syncthreads();
        // P2: 4 rows x 4 cols; 1 global b128 (Wh, L2) + 1 LDS b128 (plT) per m
        float a[4][4];
#pragma unroll
        for (int rr = 0; rr < 4; ++rr)
#pragma unroll
            for (int c = 0; c < 4; ++c) a[rr][c] = 0.f;
#pragma unroll 4
        for (int m = gm; m < 400; m += 32) {
            float4 w4 = WhG[m * 8 + kq];
            float4 p4 = plT[m];
            a[0][0] += p4.x * w4.x; a[0][1] += p4.x * w4.y; a[0][2] += p4.x * w4.z; a[0][3] += p4.x * w4.w;
            a[1][0] += p4.y * w4.x; a[1][1] += p4.y * w4.y; a[1][2] += p4.y * w4.z; a[1][3] += p4.y * w4.w;
            a[2][0] += p4.z * w4.x; a[2][1] += p4.z * w4.y; a[2][2] += p4.z * w4.z; a[2][3] += p4.z * w4.w;
            a[3][0] += p4.w * w4.x; a[3][1] += p4.w * w4.y; a[3][2] += p4.w * w4.z; a[3][3] += p4.w * w4.w;
        }
#pragma unroll
        for (int rr = 0; rr < 4; ++rr)
#pragma unroll
            for (int c = 0; c < 4; ++c) {
                float v = a[rr][c];
                v += __shfl_xor(v, 1, 64);             // DPP, off the LDS pipe
                v += __shfl_xor(v, 2, 64);
                v += __shfl_xor(v, 4, 64);
                a[rr][c] = v;
            }
        if (g == 0) {
#pragma unroll
            for (int rr = 0; rr < 4; ++rr)
#pragma unroll
                for (int c = 0; c < 4; ++c) red[wv][kq][rr][c] = a[rr][c];
        }
        __syncthreads();
        // P3: combine 4 wave-partials, normalize, elu, store
        if (t < 128) {
            int rw3 = t >> 5, kk = t & 31;
            int q3 = kk >> 2, c3 = kk & 3;
            float s = sred[it & 1][rw3][0] + sred[it & 1][rw3][1]
                    + sred[it & 1][rw3][2] + sred[it & 1][rw3][3];
            float o = (red[0][q3][rw3][c3] + red[1][q3][rw3][c3]
                     + red[2][q3][rw3][c3] + red[3][q3][rw3][c3]) / s;
            o = o > 0.f ? o : (__expf(o) - 1.f);       // elu
            int n = n0 + it * 4 + rw3;
            if (n > 399) n = 399;                      // clamped dup: same value
            xout[(b * 400 + n) * 256 + h * 32 + kk] = o;
        }
        __syncthreads();
    }
}

// ---------- S6: out[r][v] = sum_d x[b,250+dn,d]*Wb[d][v] + b[v]
__global__ __launch_bounds__(256) void k_out(const float* x, const unsigned short* Wb,
                                             const float* bias, float* out) {
    int vt = blockIdx.x, rg = blockIdx.y, t = threadIdx.x;  // grid (10,50)
    __shared__ float xr[6][256];
    int r0 = rg * 6;
    int b = r0 / 150, n0 = 250 + (r0 % 150);
    for (int i = t; i < 1536; i += 256) {
        int rr = i >> 8, dd = i & 255;
        xr[rr][dd] = x[(b * 400 + n0 + rr) * 256 + dd];
    }
    __syncthreads();
    int v = vt * 512 + t * 2;
    if (v >= 5000) return;
    float acc[6][2];
#pragma unroll
    for (int rr = 0; rr < 6; ++rr) { acc[rr][0] = 0.f; acc[rr][1] = 0.f; }
    const unsigned short* Wp = Wb + v;
#pragma unroll 8
    for (int dd = 0; dd < 256; ++dd) {
        unsigned int wu = *reinterpret_cast<const unsigned int*>(Wp + dd * 5000);
        float w0 = bf2f_raw(wu & 0xFFFFu);
        float w1 = bf2f_raw(wu >> 16);
#pragma unroll
        for (int rr = 0; rr < 6; ++rr) {
            float xv = xr[rr][dd];
            acc[rr][0] += xv * w0;
            acc[rr][1] += xv * w1;
        }
    }
    float b0 = bias[v], b1 = bias[v + 1];
#pragma unroll
    for (int rr = 0; rr < 6; ++rr) {
        out[(r0 + rr) * 5000 + v]     = acc[rr][0] + b0;
        out[(r0 + rr) * 5000 + v + 1] = acc[rr][1] + b1;
    }
}

extern "C" void kernel_launch(void* const* d_in, const int* in_sizes, int n_in,
                              void* d_out, int out_size, void* d_ws, size_t ws_size,
                              hipStream_t stream) {
    const int*   enc   = (const int*)d_in[0];
    const int*   dec   = (const int*)d_in[1];
    const float* emb   = (const float*)d_in[3];
    const float* convw = (const float*)d_in[4];
    const float* convb = (const float*)d_in[5];
    const float* hstW  = (const float*)d_in[6];
    const float* hstb  = (const float*)d_in[7];
    const float* attW  = (const float*)d_in[15];
    const float* a1    = (const float*)d_in[16];
    const float* a2    = (const float*)d_in[17];
    const float* outW  = (const float*)d_in[18];
    const float* outb  = (const float*)d_in[19];
    float* out = (float*)d_out;

    char* ws = (char*)d_ws;
    float* T    = (float*)ws; ws += 5 * 128 * 128 * 4;
    float* WhA  = (float*)ws; ws += 16 * 400 * 32 * 4;
    float* WhB  = (float*)ws; ws += 16 * 400 * 32 * 4;
    float* f1A  = (float*)ws; ws += 16 * 400 * 4;
    float* f2A  = (float*)ws; ws += 16 * 400 * 4;
    float* f1B  = (float*)ws; ws += 16 * 400 * 4;
    float* f2B  = (float*)ws; ws += 16 * 400 * 4;
    float* x1   = (float*)ws; ws += 800 * 256 * 4;
    float* x2   = (float*)ws; ws += 800 * 256 * 4;
    unsigned short* Wb = (unsigned short*)ws; ws += 256 * 5000 * 2;

    k_prep<<<2628, 256, 0, stream>>>(emb, convw, T, outW, Wb);
    k_convwh<<<400, 256, 0, stream>>>(enc, dec, convb, T, hstW, hstb, attW,
                                      a1, a2, WhA, f1A, f2A);
    k_attn<<<dim3(50, 16), 256, 0, stream>>>(WhA, f1A, f2A, x1, 0);
    k_wh<<<400, 256, 0, stream>>>(x1, attW, a1, a2, WhB, f1B, f2B);
    k_attn<<<dim3(19, 16), 256, 0, stream>>>(WhB, f1B, f2B, x2, 250);
    k_out<<<dim3(10, 50), 256, 0, stream>>>(x2, Wb, outb, out);
}